// Round 1
// baseline (519.132 us; speedup 1.0000x reference)
//
#include <hip/hip_runtime.h>

// SkipGram negative-sampling loss, MI355X (gfx950).
// Inputs (setup_inputs order):
//   d_in[0] center   int32 [32768]
//   d_in[1] context  int32 [32768]
//   d_in[2] noise    int32 [32768*15]
//   d_in[3] drop_u   f32   [32768,512]
//   d_in[4] Wc       f32   [100000,512]
//   d_in[5] Wx       f32   [100000,512]
// Output: scalar f32 loss.

constexpr int EMB    = 512;
constexpr int BATCH  = 32768;
constexpr int NEGS   = 15;
constexpr float DROP_P = 0.1f;

constexpr int WAVES_PER_BLOCK = 4;            // 256 threads
constexpr int NBLOCKS = BATCH / WAVES_PER_BLOCK;  // 8192

__device__ __forceinline__ float lsig(float x) {
    // log_sigmoid(x) = min(x,0) - log1p(exp(-|x|)), numerically stable
    return fminf(x, 0.0f) - log1pf(__expf(-fabsf(x)));
}

__device__ __forceinline__ float dot8(const float4& a0, const float4& a1,
                                      const float4& c0, const float4& c1) {
    float d = a0.x * c0.x;
    d = fmaf(a0.y, c0.y, d);
    d = fmaf(a0.z, c0.z, d);
    d = fmaf(a0.w, c0.w, d);
    d = fmaf(a1.x, c1.x, d);
    d = fmaf(a1.y, c1.y, d);
    d = fmaf(a1.z, c1.z, d);
    d = fmaf(a1.w, c1.w, d);
    return d;
}

__global__ __launch_bounds__(256) void skipgram_main(
    const int*   __restrict__ center,
    const int*   __restrict__ context,
    const int*   __restrict__ noise_idx,
    const float* __restrict__ drop_u,
    const float* __restrict__ Wc,
    const float* __restrict__ Wx,
    float*       __restrict__ block_sums)
{
    const int lane = threadIdx.x & 63;
    const int wave = threadIdx.x >> 6;
    const int b    = blockIdx.x * WAVES_PER_BLOCK + wave;

    // ---- load center embedding row + dropout mask (64 lanes x 8 f32 = 512) ----
    const float4* cen_row = (const float4*)(Wc     + (size_t)center[b] * EMB);
    const float4* du_row  = (const float4*)(drop_u + (size_t)b         * EMB);
    float4 c0 = cen_row[lane * 2 + 0];
    float4 c1 = cen_row[lane * 2 + 1];
    float4 u0 = du_row[lane * 2 + 0];
    float4 u1 = du_row[lane * 2 + 1];
    const float ks = 1.0f / (1.0f - DROP_P);
    c0.x = (u0.x >= DROP_P) ? c0.x * ks : 0.0f;
    c0.y = (u0.y >= DROP_P) ? c0.y * ks : 0.0f;
    c0.z = (u0.z >= DROP_P) ? c0.z * ks : 0.0f;
    c0.w = (u0.w >= DROP_P) ? c0.w * ks : 0.0f;
    c1.x = (u1.x >= DROP_P) ? c1.x * ks : 0.0f;
    c1.y = (u1.y >= DROP_P) ? c1.y * ks : 0.0f;
    c1.z = (u1.z >= DROP_P) ? c1.z * ks : 0.0f;
    c1.w = (u1.w >= DROP_P) ? c1.w * ks : 0.0f;

    // ---- 16 dot products (1 positive + 15 negative rows of Wx) ----
    float dots[1 + NEGS];
    {
        const float4* r = (const float4*)(Wx + (size_t)context[b] * EMB);
        float4 a0 = r[lane * 2 + 0];
        float4 a1 = r[lane * 2 + 1];
        dots[0] = dot8(a0, a1, c0, c1);
    }
#pragma unroll
    for (int k = 0; k < NEGS; ++k) {
        const float4* r = (const float4*)(Wx + (size_t)noise_idx[b * NEGS + k] * EMB);
        float4 a0 = r[lane * 2 + 0];
        float4 a1 = r[lane * 2 + 1];
        dots[1 + k] = dot8(a0, a1, c0, c1);
    }

    // ---- butterfly reduce all 16 dots across the 64-lane wave ----
#pragma unroll
    for (int off = 32; off; off >>= 1) {
#pragma unroll
        for (int i = 0; i < 1 + NEGS; ++i)
            dots[i] += __shfl_xor(dots[i], off, 64);
    }

    __shared__ float wsum[WAVES_PER_BLOCK];
    if (lane == 0) {
        float loss = lsig(dots[0]);          // positive: logsigmoid(ctx . cen)
#pragma unroll
        for (int k = 1; k <= NEGS; ++k)
            loss += lsig(-dots[k]);          // negative: logsigmoid(-neg . cen)
        wsum[wave] = -loss;                  // per-element contribution to -(...)
    }
    __syncthreads();
    if (threadIdx.x == 0) {
        float s = 0.0f;
#pragma unroll
        for (int w = 0; w < WAVES_PER_BLOCK; ++w) s += wsum[w];
        block_sums[blockIdx.x] = s;
    }
}

__global__ __launch_bounds__(256) void skipgram_reduce(
    const float* __restrict__ block_sums, float* __restrict__ out)
{
    float acc = 0.0f;
    for (int i = threadIdx.x; i < NBLOCKS; i += 256) acc += block_sums[i];
#pragma unroll
    for (int off = 32; off; off >>= 1) acc += __shfl_xor(acc, off, 64);
    __shared__ float w[4];
    const int lane = threadIdx.x & 63, wv = threadIdx.x >> 6;
    if (lane == 0) w[wv] = acc;
    __syncthreads();
    if (threadIdx.x == 0)
        out[0] = (w[0] + w[1] + w[2] + w[3]) * (1.0f / (float)BATCH);
}

extern "C" void kernel_launch(void* const* d_in, const int* in_sizes, int n_in,
                              void* d_out, int out_size, void* d_ws, size_t ws_size,
                              hipStream_t stream) {
    const int*   center  = (const int*)d_in[0];
    const int*   context = (const int*)d_in[1];
    const int*   noise   = (const int*)d_in[2];
    const float* drop_u  = (const float*)d_in[3];
    const float* Wc      = (const float*)d_in[4];
    const float* Wx      = (const float*)d_in[5];
    float* out = (float*)d_out;
    float* bs  = (float*)d_ws;   // NBLOCKS floats = 32 KiB of scratch

    skipgram_main<<<NBLOCKS, 256, 0, stream>>>(center, context, noise,
                                               drop_u, Wc, Wx, bs);
    skipgram_reduce<<<1, 256, 0, stream>>>(bs, out);
}

// Round 2
// 510.002 us; speedup vs baseline: 1.0179x; 1.0179x over previous
//
#include <hip/hip_runtime.h>

// SkipGram negative-sampling loss, MI355X (gfx950).
// Inputs (setup_inputs order):
//   d_in[0] center   int32 [32768]
//   d_in[1] context  int32 [32768]
//   d_in[2] noise    int32 [32768*15]
//   d_in[3] drop_u   f32   [32768,512]
//   d_in[4] Wc       f32   [100000,512]
//   d_in[5] Wx       f32   [100000,512]
// Output: scalar f32 loss.
//
// R1: value-halving butterfly reduction (21 shfls vs 96) + parallel lsig
//     across lanes + grouped row loads (4 rows / 4 KB in flight per wave).

constexpr int EMB    = 512;
constexpr int BATCH  = 32768;
constexpr int NEGS   = 15;
constexpr float DROP_P = 0.1f;

constexpr int WAVES_PER_BLOCK = 4;                // 256 threads
constexpr int NBLOCKS = BATCH / WAVES_PER_BLOCK;  // 8192

__device__ __forceinline__ float lsig(float x) {
    // log_sigmoid(x) = min(x,0) - log1p(exp(-|x|)), numerically stable
    return fminf(x, 0.0f) - log1pf(__expf(-fabsf(x)));
}

__device__ __forceinline__ float dot8(const float4& a0, const float4& a1,
                                      const float4& c0, const float4& c1) {
    float d = a0.x * c0.x;
    d = fmaf(a0.y, c0.y, d);
    d = fmaf(a0.z, c0.z, d);
    d = fmaf(a0.w, c0.w, d);
    d = fmaf(a1.x, c1.x, d);
    d = fmaf(a1.y, c1.y, d);
    d = fmaf(a1.z, c1.z, d);
    d = fmaf(a1.w, c1.w, d);
    return d;
}

__global__ __launch_bounds__(256) void skipgram_main(
    const int*   __restrict__ center,
    const int*   __restrict__ context,
    const int*   __restrict__ noise_idx,
    const float* __restrict__ drop_u,
    const float* __restrict__ Wc,
    const float* __restrict__ Wx,
    float*       __restrict__ block_sums)
{
    const int lane = threadIdx.x & 63;
    const int wave = threadIdx.x >> 6;
    const int b    = blockIdx.x * WAVES_PER_BLOCK + wave;

    // ---- load center embedding row + dropout mask (64 lanes x 8 f32 = 512) ----
    const float4* cen_row = (const float4*)(Wc     + (size_t)center[b] * EMB);
    const float4* du_row  = (const float4*)(drop_u + (size_t)b         * EMB);
    float4 c0 = cen_row[lane * 2 + 0];
    float4 c1 = cen_row[lane * 2 + 1];
    float4 u0 = du_row[lane * 2 + 0];
    float4 u1 = du_row[lane * 2 + 1];
    const float ks = 1.0f / (1.0f - DROP_P);
    c0.x = (u0.x >= DROP_P) ? c0.x * ks : 0.0f;
    c0.y = (u0.y >= DROP_P) ? c0.y * ks : 0.0f;
    c0.z = (u0.z >= DROP_P) ? c0.z * ks : 0.0f;
    c0.w = (u0.w >= DROP_P) ? c0.w * ks : 0.0f;
    c1.x = (u1.x >= DROP_P) ? c1.x * ks : 0.0f;
    c1.y = (u1.y >= DROP_P) ? c1.y * ks : 0.0f;
    c1.z = (u1.z >= DROP_P) ? c1.z * ks : 0.0f;
    c1.w = (u1.w >= DROP_P) ? c1.w * ks : 0.0f;

    // ---- 16 row indices: row 0 = context (positive), rows 1..15 = negatives ----
    int ridx[16];
    ridx[0] = context[b];
#pragma unroll
    for (int k = 0; k < NEGS; ++k) ridx[1 + k] = noise_idx[b * NEGS + k];

    // ---- 16 dot products, loads batched 4 rows (4 KB) at a time ----
    float dots[16];
#pragma unroll
    for (int g = 0; g < 16; g += 4) {
        float4 a0[4], a1[4];
#pragma unroll
        for (int j = 0; j < 4; ++j) {
            const float4* r = (const float4*)(Wx + (size_t)ridx[g + j] * EMB);
            a0[j] = r[lane * 2 + 0];
            a1[j] = r[lane * 2 + 1];
        }
#pragma unroll
        for (int j = 0; j < 4; ++j)
            dots[g + j] = dot8(a0[j], a1[j], c0, c1);
    }

    // ---- value-halving butterfly: 16 values x 64 lanes -> each lane holds
    //      dot[(lane>>2)&15] reduced over its mod-4 lane class (15 shfls) ----
    const bool b5 = (lane & 32) != 0;
    const bool b4 = (lane & 16) != 0;
    const bool b3 = (lane & 8)  != 0;
    const bool b2 = (lane & 4)  != 0;

    float h8[8];
#pragma unroll
    for (int i = 0; i < 8; ++i) {
        float keep = b5 ? dots[i + 8] : dots[i];
        float send = b5 ? dots[i]     : dots[i + 8];
        h8[i] = keep + __shfl_xor(send, 32, 64);
    }
    float h4[4];
#pragma unroll
    for (int i = 0; i < 4; ++i) {
        float keep = b4 ? h8[i + 4] : h8[i];
        float send = b4 ? h8[i]     : h8[i + 4];
        h4[i] = keep + __shfl_xor(send, 16, 64);
    }
    float h2[2];
#pragma unroll
    for (int i = 0; i < 2; ++i) {
        float keep = b3 ? h4[i + 2] : h4[i];
        float send = b3 ? h4[i]     : h4[i + 2];
        h2[i] = keep + __shfl_xor(send, 8, 64);
    }
    float d;
    {
        float keep = b2 ? h2[1] : h2[0];
        float send = b2 ? h2[0] : h2[1];
        d = keep + __shfl_xor(send, 4, 64);
    }
    // finish the lane sum over bits [1:0] (same dot index on partners)
    d += __shfl_xor(d, 1, 64);
    d += __shfl_xor(d, 2, 64);
    // now every lane: d = full dot[(lane>>2)&15], replicated x4

    // ---- parallel logsigmoid + cross-row sum ----
    const int v = (lane >> 2) & 15;
    float term = lsig(v == 0 ? d : -d);   // positive row gets +d, negatives -d
    term += __shfl_xor(term, 4, 64);
    term += __shfl_xor(term, 8, 64);
    term += __shfl_xor(term, 16, 64);
    term += __shfl_xor(term, 32, 64);
    // every lane now holds sum over the 16 rows

    __shared__ float wsum[WAVES_PER_BLOCK];
    if (lane == 0) wsum[wave] = -term;
    __syncthreads();
    if (threadIdx.x == 0) {
        float s = 0.0f;
#pragma unroll
        for (int w = 0; w < WAVES_PER_BLOCK; ++w) s += wsum[w];
        block_sums[blockIdx.x] = s;
    }
}

__global__ __launch_bounds__(256) void skipgram_reduce(
    const float* __restrict__ block_sums, float* __restrict__ out)
{
    float acc = 0.0f;
    for (int i = threadIdx.x; i < NBLOCKS; i += 256) acc += block_sums[i];
#pragma unroll
    for (int off = 32; off; off >>= 1) acc += __shfl_xor(acc, off, 64);
    __shared__ float w[4];
    const int lane = threadIdx.x & 63, wv = threadIdx.x >> 6;
    if (lane == 0) w[wv] = acc;
    __syncthreads();
    if (threadIdx.x == 0)
        out[0] = (w[0] + w[1] + w[2] + w[3]) * (1.0f / (float)BATCH);
}

extern "C" void kernel_launch(void* const* d_in, const int* in_sizes, int n_in,
                              void* d_out, int out_size, void* d_ws, size_t ws_size,
                              hipStream_t stream) {
    const int*   center  = (const int*)d_in[0];
    const int*   context = (const int*)d_in[1];
    const int*   noise   = (const int*)d_in[2];
    const float* drop_u  = (const float*)d_in[3];
    const float* Wc      = (const float*)d_in[4];
    const float* Wx      = (const float*)d_in[5];
    float* out = (float*)d_out;
    float* bs  = (float*)d_ws;   // NBLOCKS floats = 32 KiB of scratch

    skipgram_main<<<NBLOCKS, 256, 0, stream>>>(center, context, noise,
                                               drop_u, Wc, Wx, bs);
    skipgram_reduce<<<1, 256, 0, stream>>>(bs, out);
}